// Round 1
// baseline (392.167 us; speedup 1.0000x reference)
//
#include <hip/hip_runtime.h>
#include <hip/hip_bf16.h>
#include <math.h>

typedef unsigned short ushort_t;
typedef short bf16x8 __attribute__((ext_vector_type(8)));
typedef float f32x4 __attribute__((ext_vector_type(4)));

#define NH 16
#define DH 128
#define DM 2048
#define TSEQ 2048
#define BT 4096   // B*T

__device__ __forceinline__ void async16(const void* g, void* l) {
  __builtin_amdgcn_global_load_lds(
      (const __attribute__((address_space(1))) void*)g,
      (__attribute__((address_space(3))) void*)l, 16, 0, 0);
}

__device__ __forceinline__ f32x4 mfma16(bf16x8 a, bf16x8 b, f32x4 c) {
  return __builtin_amdgcn_mfma_f32_16x16x32_bf16(a, b, c, 0, 0, 0);
}

__device__ __forceinline__ ushort_t f2bf(float f) {
  __hip_bfloat16 h = __float2bfloat16(f);
  return *reinterpret_cast<ushort_t*>(&h);
}

// ---------------- fp32 -> bf16 conversion ----------------
__global__ void cvt_kernel(const float* __restrict__ in, ushort_t* __restrict__ out, int n4) {
  const int i = blockIdx.x * blockDim.x + threadIdx.x;
  if (i >= n4) return;
  const float4 v = reinterpret_cast<const float4*>(in)[i];
  ushort4 u;
  u.x = f2bf(v.x); u.y = f2bf(v.y); u.z = f2bf(v.z); u.w = f2bf(v.w);
  reinterpret_cast<ushort4*>(out)[i] = u;
}

// ---------------- GEMM: C = A[M,K] * W[N,K]^T + bias ----------------
// MODE 0: QKV fused (blockIdx.z = 0/1/2 -> Q, K, Vt outputs, bf16 scattered)
// MODE 1: out projection (fp32 linear output)
template<int MODE>
__global__ __launch_bounds__(256)
void gemm_kernel(const ushort_t* __restrict__ A,
                 const ushort_t* __restrict__ W_0, const ushort_t* __restrict__ W_1,
                 const ushort_t* __restrict__ W_2,
                 const float* __restrict__ b_0, const float* __restrict__ b_1,
                 const float* __restrict__ b_2,
                 ushort_t* __restrict__ outQ, ushort_t* __restrict__ outK,
                 ushort_t* __restrict__ outVt, float* __restrict__ outF)
{
  constexpr int K = DM;
  __shared__ __attribute__((aligned(16))) ushort_t As[128 * 64];
  __shared__ __attribute__((aligned(16))) ushort_t Bs[128 * 64];

  const int z = (MODE == 0) ? blockIdx.z : 0;
  const ushort_t* Wp = (MODE == 0) ? (z == 0 ? W_0 : (z == 1 ? W_1 : W_2)) : W_0;
  const float* bias  = (MODE == 0) ? (z == 0 ? b_0 : (z == 1 ? b_1 : b_2)) : b_0;

  const int n0 = blockIdx.x * 128;
  const int m0 = blockIdx.y * 128;
  const int tid = threadIdx.x;
  const int w = tid >> 6, l = tid & 63;
  const int wm = w >> 1, wn = w & 1;
  const int l15 = l & 15, l4 = l >> 4;

  f32x4 zero = {0.f, 0.f, 0.f, 0.f};
  f32x4 acc[4][4];
#pragma unroll
  for (int i = 0; i < 4; ++i)
#pragma unroll
    for (int j = 0; j < 4; ++j) acc[i][j] = zero;

  for (int k0 = 0; k0 < K; k0 += 64) {
    __syncthreads();
#pragma unroll
    for (int i = 0; i < 4; ++i) {
      const int rb = (i * 4 + w) * 8;
      const int r = rb + (l >> 3);
      const int c = ((l & 7) * 8) ^ ((r & 7) * 8);   // pre-swizzled source col
      async16(A  + (size_t)(m0 + r) * K + k0 + c, &As[rb * 64]);
      async16(Wp + (size_t)(n0 + r) * K + k0 + c, &Bs[rb * 64]);
    }
    __syncthreads();
#pragma unroll
    for (int ks = 0; ks < 2; ++ks) {
      bf16x8 af[4], bfr[4];
#pragma unroll
      for (int mf = 0; mf < 4; ++mf) {
        const int row = wm * 64 + mf * 16 + l15;
        const int byte_ = row * 128 + ((l4 * 16 + ks * 64) ^ ((row & 7) << 4));
        af[mf] = *reinterpret_cast<const bf16x8*>(reinterpret_cast<const char*>(As) + byte_);
      }
#pragma unroll
      for (int nf = 0; nf < 4; ++nf) {
        const int row = wn * 64 + nf * 16 + l15;
        const int byte_ = row * 128 + ((l4 * 16 + ks * 64) ^ ((row & 7) << 4));
        bfr[nf] = *reinterpret_cast<const bf16x8*>(reinterpret_cast<const char*>(Bs) + byte_);
      }
#pragma unroll
      for (int mf = 0; mf < 4; ++mf)
#pragma unroll
        for (int nf = 0; nf < 4; ++nf)
          acc[mf][nf] = mfma16(af[mf], bfr[nf], acc[mf][nf]);
    }
  }

  // epilogue
#pragma unroll
  for (int nf = 0; nf < 4; ++nf) {
    const int n = n0 + wn * 64 + nf * 16 + l15;
    const float bv = bias[n];
#pragma unroll
    for (int mf = 0; mf < 4; ++mf) {
#pragma unroll
      for (int r = 0; r < 4; ++r) {
        const int m = m0 + wm * 64 + mf * 16 + l4 * 4 + r;
        const float v = acc[mf][nf][r] + bv;
        if (MODE == 1) {
          outF[(size_t)m * DM + n] = v;
        } else {
          const int b = m >> 11, t = m & 2047;
          const int hh = n >> 7, d = n & 127;
          const ushort_t val = f2bf(v);
          if (z == 2) {
            outVt[((size_t)(b * NH + hh) * DH + d) * TSEQ + t] = val;   // V transposed
          } else {
            ushort_t* dst = (z == 0) ? outQ : outK;
            dst[((size_t)(b * NH + hh) * TSEQ + t) * DH + d] = val;
          }
        }
      }
    }
  }
}

// ---------------- causal flash attention ----------------
// grid: (32 q-tiles, 32 b*h). block 256 = 4 waves, each wave 16 q rows.
__global__ __launch_bounds__(256)
void attn_kernel(const ushort_t* __restrict__ Q, const ushort_t* __restrict__ Kg,
                 const ushort_t* __restrict__ Vt, ushort_t* __restrict__ ctx)
{
  __shared__ __attribute__((aligned(16))) ushort_t Ks[64 * 128];   // [kv][d]
  __shared__ __attribute__((aligned(16))) ushort_t Vs[128 * 64];   // [d][kv]
  __shared__ __attribute__((aligned(16))) ushort_t Ps[4][16 * 72]; // per-wave P, pitch 72

  const int qt = (int)gridDim.x - 1 - (int)blockIdx.x;   // heavy tiles dispatch first
  const int bh = blockIdx.y;
  const int tid = threadIdx.x, w = tid >> 6, l = tid & 63;
  const int l15 = l & 15, l4 = l >> 4;
  const size_t kbase = (size_t)bh * TSEQ * DH;
  const size_t vbase = (size_t)bh * DH * TSEQ;
  const int qrow0 = qt * 64 + w * 16;

  // Q fragments in registers for the whole kernel
  bf16x8 aq[4];
  {
    const ushort_t* qp = Q + kbase + (size_t)(qrow0 + l15) * DH + l4 * 8;
#pragma unroll
    for (int ks = 0; ks < 4; ++ks)
      aq[ks] = *reinterpret_cast<const bf16x8*>(qp + ks * 32);
  }

  f32x4 zero = {0.f, 0.f, 0.f, 0.f};
  f32x4 o[8];
#pragma unroll
  for (int i = 0; i < 8; ++i) o[i] = zero;
  float m_r[4], l_r[4];
#pragma unroll
  for (int r = 0; r < 4; ++r) { m_r[r] = -__builtin_inff(); l_r[r] = 0.f; }
  const float scale = 0.08838834764831845f;   // 1/sqrt(128)

  for (int kt = 0; kt <= qt; ++kt) {
    const int kv0 = kt * 64;
    __syncthreads();
    // stage K tile [64][128]
#pragma unroll
    for (int i = 0; i < 4; ++i) {
      const int rb = (i * 4 + w) * 4;
      const int r = rb + l4;
      const int c = (l15 * 8) ^ ((r & 7) * 8);
      async16(Kg + kbase + (size_t)(kv0 + r) * DH + c, &Ks[rb * DH]);
    }
    // stage V^T tile [128][64]
#pragma unroll
    for (int i = 0; i < 4; ++i) {
      const int rb = (i * 4 + w) * 8;
      const int d = rb + (l >> 3);
      const int c = ((l & 7) * 8) ^ ((d & 7) * 8);
      async16(Vt + vbase + (size_t)d * TSEQ + kv0 + c, &Vs[rb * 64]);
    }
    __syncthreads();

    // S = Q K^T (per wave: 16 q rows x 64 kv)
    f32x4 s[4];
#pragma unroll
    for (int nf = 0; nf < 4; ++nf) {
      s[nf] = zero;
#pragma unroll
      for (int ks = 0; ks < 4; ++ks) {
        const int row = nf * 16 + l15;
        const int byte_ = row * 256 + ((l4 * 16 + ks * 64) ^ ((row & 7) << 4));
        bf16x8 kb = *reinterpret_cast<const bf16x8*>(reinterpret_cast<const char*>(Ks) + byte_);
        s[nf] = mfma16(aq[ks], kb, s[nf]);
      }
    }

    // scale + causal mask
#pragma unroll
    for (int nf = 0; nf < 4; ++nf)
#pragma unroll
      for (int r = 0; r < 4; ++r) {
        float v = s[nf][r] * scale;
        if (kt == qt) {
          const int kvg = kv0 + nf * 16 + l15;
          const int qg = qrow0 + l4 * 4 + r;
          if (kvg > qg) v = -__builtin_inff();
        }
        s[nf][r] = v;
      }

    // online softmax
    float rmax[4], alpha[4], psum[4];
#pragma unroll
    for (int r = 0; r < 4; ++r)
      rmax[r] = fmaxf(fmaxf(s[0][r], s[1][r]), fmaxf(s[2][r], s[3][r]));
#pragma unroll
    for (int mk = 1; mk < 16; mk <<= 1)
#pragma unroll
      for (int r = 0; r < 4; ++r)
        rmax[r] = fmaxf(rmax[r], __shfl_xor(rmax[r], mk));
#pragma unroll
    for (int r = 0; r < 4; ++r) {
      const float mnew = fmaxf(m_r[r], rmax[r]);
      alpha[r] = __expf(m_r[r] - mnew);
      m_r[r] = mnew;
      float ps = 0.f;
#pragma unroll
      for (int nf = 0; nf < 4; ++nf) {
        const float p = __expf(s[nf][r] - mnew);
        s[nf][r] = p;
        ps += p;
      }
      psum[r] = ps;
    }
#pragma unroll
    for (int mk = 1; mk < 16; mk <<= 1)
#pragma unroll
      for (int r = 0; r < 4; ++r)
        psum[r] += __shfl_xor(psum[r], mk);
#pragma unroll
    for (int r = 0; r < 4; ++r)
      l_r[r] = l_r[r] * alpha[r] + psum[r];
#pragma unroll
    for (int df = 0; df < 8; ++df)
#pragma unroll
      for (int r = 0; r < 4; ++r)
        o[df][r] *= alpha[r];

    // P (bf16) to wave-private LDS, then PV
#pragma unroll
    for (int nf = 0; nf < 4; ++nf)
#pragma unroll
      for (int r = 0; r < 4; ++r)
        Ps[w][(l4 * 4 + r) * 72 + nf * 16 + l15] = f2bf(s[nf][r]);

    asm volatile("s_waitcnt lgkmcnt(0)" ::: "memory");

#pragma unroll
    for (int ks2 = 0; ks2 < 2; ++ks2) {
      bf16x8 pa = *reinterpret_cast<const bf16x8*>(&Ps[w][l15 * 72 + ks2 * 32 + l4 * 8]);
#pragma unroll
      for (int df = 0; df < 8; ++df) {
        const int d = df * 16 + l15;
        const int byte_ = d * 128 + ((l4 * 16 + ks2 * 64) ^ ((d & 7) << 4));
        bf16x8 vb = *reinterpret_cast<const bf16x8*>(reinterpret_cast<const char*>(Vs) + byte_);
        o[df] = mfma16(pa, vb, o[df]);
      }
    }
  }

  // epilogue: normalize, write merged ctx [B,T,D] bf16
  const size_t obase = (size_t)(bh >> 4) * TSEQ * DM + (size_t)(bh & 15) * DH;
#pragma unroll
  for (int r = 0; r < 4; ++r) {
    const float inv = 1.0f / l_r[r];
    const int q = qrow0 + l4 * 4 + r;
#pragma unroll
    for (int df = 0; df < 8; ++df) {
      const int d = df * 16 + l15;
      ctx[obase + (size_t)q * DM + d] = f2bf(o[df][r] * inv);
    }
  }
}

extern "C" void kernel_launch(void* const* d_in, const int* in_sizes, int n_in,
                              void* d_out, int out_size, void* d_ws, size_t ws_size,
                              hipStream_t stream) {
  const float* x  = (const float*)d_in[0];
  const float* Wq = (const float*)d_in[1];
  const float* bq = (const float*)d_in[2];
  const float* Wk = (const float*)d_in[3];
  const float* bk = (const float*)d_in[4];
  const float* Wv = (const float*)d_in[5];
  const float* bv = (const float*)d_in[6];
  const float* Wo = (const float*)d_in[7];
  const float* bo = (const float*)d_in[8];
  float* out = (float*)d_out;

  char* ws = (char*)d_ws;
  ushort_t* xb  = (ushort_t*)ws;  ws += (size_t)BT * DM * 2;      // x bf16; reused as ctx
  ushort_t* Wqb = (ushort_t*)ws;  ws += (size_t)DM * DM * 2;
  ushort_t* Wkb = (ushort_t*)ws;  ws += (size_t)DM * DM * 2;
  ushort_t* Wvb = (ushort_t*)ws;  ws += (size_t)DM * DM * 2;
  ushort_t* Wob = (ushort_t*)ws;  ws += (size_t)DM * DM * 2;
  ushort_t* Qb  = (ushort_t*)ws;  ws += (size_t)BT * DM * 2;
  ushort_t* Kb  = (ushort_t*)ws;  ws += (size_t)BT * DM * 2;
  ushort_t* Vtb = (ushort_t*)ws;  ws += (size_t)BT * DM * 2;
  ushort_t* ctxb = xb;   // alias: x dead after QKV GEMM

  const int nx4 = BT * DM / 4, nw4 = DM * DM / 4;
  cvt_kernel<<<nx4 / 256, 256, 0, stream>>>(x,  xb,  nx4);
  cvt_kernel<<<nw4 / 256, 256, 0, stream>>>(Wq, Wqb, nw4);
  cvt_kernel<<<nw4 / 256, 256, 0, stream>>>(Wk, Wkb, nw4);
  cvt_kernel<<<nw4 / 256, 256, 0, stream>>>(Wv, Wvb, nw4);
  cvt_kernel<<<nw4 / 256, 256, 0, stream>>>(Wo, Wob, nw4);

  gemm_kernel<0><<<dim3(DM / 128, BT / 128, 3), 256, 0, stream>>>(
      xb, Wqb, Wkb, Wvb, bq, bk, bv, Qb, Kb, Vtb, nullptr);

  attn_kernel<<<dim3(TSEQ / 64, 32), 256, 0, stream>>>(Qb, Kb, Vtb, ctxb);

  gemm_kernel<1><<<dim3(DM / 128, BT / 128, 1), 256, 0, stream>>>(
      ctxb, Wob, nullptr, nullptr, bo, nullptr, nullptr,
      nullptr, nullptr, nullptr, out);
}

// Round 2
// 369.905 us; speedup vs baseline: 1.0602x; 1.0602x over previous
//
#include <hip/hip_runtime.h>
#include <hip/hip_bf16.h>
#include <math.h>

typedef unsigned short ushort_t;
typedef short bf16x8 __attribute__((ext_vector_type(8)));
typedef float f32x4 __attribute__((ext_vector_type(4)));

#define NH 16
#define DH 128
#define DM 2048
#define TSEQ 2048
#define BT 4096   // B*T

__device__ __forceinline__ void async16(const void* g, void* l) {
  __builtin_amdgcn_global_load_lds(
      (const __attribute__((address_space(1))) void*)g,
      (__attribute__((address_space(3))) void*)l, 16, 0, 0);
}

__device__ __forceinline__ f32x4 mfma16(bf16x8 a, bf16x8 b, f32x4 c) {
  return __builtin_amdgcn_mfma_f32_16x16x32_bf16(a, b, c, 0, 0, 0);
}

__device__ __forceinline__ ushort_t f2bf(float f) {
  __hip_bfloat16 h = __float2bfloat16(f);
  return *reinterpret_cast<ushort_t*>(&h);
}

// ---------------- fp32 -> bf16 conversion ----------------
__global__ void cvt_kernel(const float* __restrict__ in, ushort_t* __restrict__ out, int n4) {
  const int i = blockIdx.x * blockDim.x + threadIdx.x;
  if (i >= n4) return;
  const float4 v = reinterpret_cast<const float4*>(in)[i];
  ushort4 u;
  u.x = f2bf(v.x); u.y = f2bf(v.y); u.z = f2bf(v.z); u.w = f2bf(v.w);
  reinterpret_cast<ushort4*>(out)[i] = u;
}

// ---------------- GEMM: C = A[M,K] * W[N,K]^T + bias ----------------
// MODE 0: QKV fused (blockIdx.z = 0/1/2 -> Q, K, Vt outputs, bf16 scattered)
// MODE 1: out projection (fp32 linear output)
template<int MODE>
__global__ __launch_bounds__(256)
void gemm_kernel(const ushort_t* __restrict__ A,
                 const ushort_t* __restrict__ W_0, const ushort_t* __restrict__ W_1,
                 const ushort_t* __restrict__ W_2,
                 const float* __restrict__ b_0, const float* __restrict__ b_1,
                 const float* __restrict__ b_2,
                 ushort_t* __restrict__ outQ, ushort_t* __restrict__ outK,
                 ushort_t* __restrict__ outVt, float* __restrict__ outF)
{
  constexpr int K = DM;
  __shared__ __attribute__((aligned(16))) ushort_t As[128 * 64];
  __shared__ __attribute__((aligned(16))) ushort_t Bs[128 * 64];

  const int z = (MODE == 0) ? blockIdx.z : 0;
  const ushort_t* Wp = (MODE == 0) ? (z == 0 ? W_0 : (z == 1 ? W_1 : W_2)) : W_0;
  const float* bias  = (MODE == 0) ? (z == 0 ? b_0 : (z == 1 ? b_1 : b_2)) : b_0;

  const int n0 = blockIdx.x * 128;
  const int m0 = blockIdx.y * 128;
  const int tid = threadIdx.x;
  const int w = tid >> 6, l = tid & 63;
  const int wm = w >> 1, wn = w & 1;
  const int l15 = l & 15, l4 = l >> 4;

  f32x4 zero = {0.f, 0.f, 0.f, 0.f};
  f32x4 acc[4][4];
#pragma unroll
  for (int i = 0; i < 4; ++i)
#pragma unroll
    for (int j = 0; j < 4; ++j) acc[i][j] = zero;

  for (int k0 = 0; k0 < K; k0 += 64) {
    __syncthreads();
#pragma unroll
    for (int i = 0; i < 4; ++i) {
      const int rb = (i * 4 + w) * 8;
      const int r = rb + (l >> 3);
      const int c = ((l & 7) * 8) ^ ((r & 7) * 8);   // pre-swizzled source col
      async16(A  + (size_t)(m0 + r) * K + k0 + c, &As[rb * 64]);
      async16(Wp + (size_t)(n0 + r) * K + k0 + c, &Bs[rb * 64]);
    }
    __syncthreads();
#pragma unroll
    for (int ks = 0; ks < 2; ++ks) {
      bf16x8 af[4], bfr[4];
#pragma unroll
      for (int mf = 0; mf < 4; ++mf) {
        const int row = wm * 64 + mf * 16 + l15;
        const int byte_ = row * 128 + ((l4 * 16 + ks * 64) ^ ((row & 7) << 4));
        af[mf] = *reinterpret_cast<const bf16x8*>(reinterpret_cast<const char*>(As) + byte_);
      }
#pragma unroll
      for (int nf = 0; nf < 4; ++nf) {
        const int row = wn * 64 + nf * 16 + l15;
        const int byte_ = row * 128 + ((l4 * 16 + ks * 64) ^ ((row & 7) << 4));
        bfr[nf] = *reinterpret_cast<const bf16x8*>(reinterpret_cast<const char*>(Bs) + byte_);
      }
#pragma unroll
      for (int mf = 0; mf < 4; ++mf)
#pragma unroll
        for (int nf = 0; nf < 4; ++nf)
          acc[mf][nf] = mfma16(af[mf], bfr[nf], acc[mf][nf]);
    }
  }

  // epilogue
#pragma unroll
  for (int nf = 0; nf < 4; ++nf) {
    const int n = n0 + wn * 64 + nf * 16 + l15;
    const float bv = bias[n];
#pragma unroll
    for (int mf = 0; mf < 4; ++mf) {
#pragma unroll
      for (int r = 0; r < 4; ++r) {
        const int m = m0 + wm * 64 + mf * 16 + l4 * 4 + r;
        const float v = acc[mf][nf][r] + bv;
        if (MODE == 1) {
          outF[(size_t)m * DM + n] = v;
        } else {
          const int b = m >> 11, t = m & 2047;
          const int hh = n >> 7, d = n & 127;
          const ushort_t val = f2bf(v);
          if (z == 2) {
            outVt[((size_t)(b * NH + hh) * DH + d) * TSEQ + t] = val;   // V transposed
          } else {
            ushort_t* dst = (z == 0) ? outQ : outK;
            dst[((size_t)(b * NH + hh) * TSEQ + t) * DH + d] = val;
          }
        }
      }
    }
  }
}

// ---------------- causal flash attention ----------------
// grid: (32 q-tiles, 32 b*h). block 256 = 4 waves, each wave 16 q rows.
// Double-buffered K/V staging with counted vmcnt prefetch (T3/T4) + setprio (T5).
__device__ __forceinline__ void stage_tiles(const ushort_t* __restrict__ Kg,
                                            const ushort_t* __restrict__ Vt,
                                            size_t kbase, size_t vbase, int kv0,
                                            ushort_t* KsBuf, ushort_t* VsBuf,
                                            int w, int l)
{
  const int l15 = l & 15, l4 = l >> 4;
#pragma unroll
  for (int i = 0; i < 4; ++i) {
    const int rb = (i * 4 + w) * 4;
    const int r = rb + l4;
    const int c = (l15 * 8) ^ ((r & 7) * 8);
    async16(Kg + kbase + (size_t)(kv0 + r) * DH + c, &KsBuf[rb * DH]);
  }
#pragma unroll
  for (int i = 0; i < 4; ++i) {
    const int rb = (i * 4 + w) * 8;
    const int d = rb + (l >> 3);
    const int c = ((l & 7) * 8) ^ ((d & 7) * 8);
    async16(Vt + vbase + (size_t)d * TSEQ + kv0 + c, &VsBuf[rb * 64]);
  }
}

__global__ __launch_bounds__(256)
void attn_kernel(const ushort_t* __restrict__ Q, const ushort_t* __restrict__ Kg,
                 const ushort_t* __restrict__ Vt, ushort_t* __restrict__ ctx)
{
  __shared__ __attribute__((aligned(16))) ushort_t Ks[2][64 * 128];   // [kv][d]
  __shared__ __attribute__((aligned(16))) ushort_t Vs[2][128 * 64];   // [d][kv]
  __shared__ __attribute__((aligned(16))) ushort_t Ps[4][16 * 72];    // per-wave P, pitch 72

  const int qt = (int)gridDim.x - 1 - (int)blockIdx.x;   // heavy tiles dispatch first
  const int bh = blockIdx.y;
  const int tid = threadIdx.x, w = tid >> 6, l = tid & 63;
  const int l15 = l & 15, l4 = l >> 4;
  const size_t kbase = (size_t)bh * TSEQ * DH;
  const size_t vbase = (size_t)bh * DH * TSEQ;
  const int qrow0 = qt * 64 + w * 16;

  // Q fragments in registers for the whole kernel
  bf16x8 aq[4];
  {
    const ushort_t* qp = Q + kbase + (size_t)(qrow0 + l15) * DH + l4 * 8;
#pragma unroll
    for (int ks = 0; ks < 4; ++ks)
      aq[ks] = *reinterpret_cast<const bf16x8*>(qp + ks * 32);
  }

  f32x4 zero = {0.f, 0.f, 0.f, 0.f};
  f32x4 o[8];
#pragma unroll
  for (int i = 0; i < 8; ++i) o[i] = zero;
  float m_r[4], l_r[4];
#pragma unroll
  for (int r = 0; r < 4; ++r) { m_r[r] = -__builtin_inff(); l_r[r] = 0.f; }
  const float scale = 0.08838834764831845f;   // 1/sqrt(128)

  // prologue: stage tile 0 into buf 0
  stage_tiles(Kg, Vt, kbase, vbase, 0, Ks[0], Vs[0], w, l);

  for (int kt = 0; kt <= qt; ++kt) {
    const int kv0 = kt * 64;
    const int cur = kt & 1;

    if (kt < qt) {
      stage_tiles(Kg, Vt, kbase, vbase, kv0 + 64, Ks[cur ^ 1], Vs[cur ^ 1], w, l);
      asm volatile("s_waitcnt vmcnt(8)" ::: "memory");   // tile kt done; kt+1 in flight
    } else {
      asm volatile("s_waitcnt vmcnt(0)" ::: "memory");
    }
    __syncthreads();   // (A) buf[cur] ready for all waves

    // S = Q K^T (per wave: 16 q rows x 64 kv)
    f32x4 s[4];
    __builtin_amdgcn_s_setprio(1);
#pragma unroll
    for (int nf = 0; nf < 4; ++nf) {
      s[nf] = zero;
#pragma unroll
      for (int ks = 0; ks < 4; ++ks) {
        const int row = nf * 16 + l15;
        const int byte_ = row * 256 + ((l4 * 16 + ks * 64) ^ ((row & 7) << 4));
        bf16x8 kb = *reinterpret_cast<const bf16x8*>(reinterpret_cast<const char*>(Ks[cur]) + byte_);
        s[nf] = mfma16(aq[ks], kb, s[nf]);
      }
    }
    __builtin_amdgcn_s_setprio(0);

    // scale + causal mask
#pragma unroll
    for (int nf = 0; nf < 4; ++nf)
#pragma unroll
      for (int r = 0; r < 4; ++r) {
        float v = s[nf][r] * scale;
        if (kt == qt) {
          const int kvg = kv0 + nf * 16 + l15;
          const int qg = qrow0 + l4 * 4 + r;
          if (kvg > qg) v = -__builtin_inff();
        }
        s[nf][r] = v;
      }

    // online softmax
    float rmax[4], alpha[4], psum[4];
#pragma unroll
    for (int r = 0; r < 4; ++r)
      rmax[r] = fmaxf(fmaxf(s[0][r], s[1][r]), fmaxf(s[2][r], s[3][r]));
#pragma unroll
    for (int mk = 1; mk < 16; mk <<= 1)
#pragma unroll
      for (int r = 0; r < 4; ++r)
        rmax[r] = fmaxf(rmax[r], __shfl_xor(rmax[r], mk));
#pragma unroll
    for (int r = 0; r < 4; ++r) {
      const float mnew = fmaxf(m_r[r], rmax[r]);
      alpha[r] = __expf(m_r[r] - mnew);
      m_r[r] = mnew;
      float ps = 0.f;
#pragma unroll
      for (int nf = 0; nf < 4; ++nf) {
        const float p = __expf(s[nf][r] - mnew);
        s[nf][r] = p;
        ps += p;
      }
      psum[r] = ps;
    }
#pragma unroll
    for (int mk = 1; mk < 16; mk <<= 1)
#pragma unroll
      for (int r = 0; r < 4; ++r)
        psum[r] += __shfl_xor(psum[r], mk);
#pragma unroll
    for (int r = 0; r < 4; ++r)
      l_r[r] = l_r[r] * alpha[r] + psum[r];
#pragma unroll
    for (int df = 0; df < 8; ++df)
#pragma unroll
      for (int r = 0; r < 4; ++r)
        o[df][r] *= alpha[r];

    // P (bf16) to wave-private LDS, then PV
#pragma unroll
    for (int nf = 0; nf < 4; ++nf)
#pragma unroll
      for (int r = 0; r < 4; ++r)
        Ps[w][(l4 * 4 + r) * 72 + nf * 16 + l15] = f2bf(s[nf][r]);

    asm volatile("s_waitcnt lgkmcnt(0)" ::: "memory");

    __builtin_amdgcn_s_setprio(1);
#pragma unroll
    for (int ks2 = 0; ks2 < 2; ++ks2) {
      bf16x8 pa = *reinterpret_cast<const bf16x8*>(&Ps[w][l15 * 72 + ks2 * 32 + l4 * 8]);
#pragma unroll
      for (int df = 0; df < 8; ++df) {
        const int d = df * 16 + l15;
        const int byte_ = d * 128 + ((l4 * 16 + ks2 * 64) ^ ((d & 7) << 4));
        bf16x8 vb = *reinterpret_cast<const bf16x8*>(reinterpret_cast<const char*>(Vs[cur]) + byte_);
        o[df] = mfma16(pa, vb, o[df]);
      }
    }
    __builtin_amdgcn_s_setprio(0);

    __syncthreads();   // (B) all waves done reading buf[cur] before next prefetch overwrites
  }

  // epilogue: normalize, write merged ctx [B,T,D] bf16
  const size_t obase = (size_t)(bh >> 4) * TSEQ * DM + (size_t)(bh & 15) * DH;
#pragma unroll
  for (int r = 0; r < 4; ++r) {
    const float inv = 1.0f / l_r[r];
    const int q = qrow0 + l4 * 4 + r;
#pragma unroll
    for (int df = 0; df < 8; ++df) {
      const int d = df * 16 + l15;
      ctx[obase + (size_t)q * DM + d] = f2bf(o[df][r] * inv);
    }
  }
}

extern "C" void kernel_launch(void* const* d_in, const int* in_sizes, int n_in,
                              void* d_out, int out_size, void* d_ws, size_t ws_size,
                              hipStream_t stream) {
  const float* x  = (const float*)d_in[0];
  const float* Wq = (const float*)d_in[1];
  const float* bq = (const float*)d_in[2];
  const float* Wk = (const float*)d_in[3];
  const float* bk = (const float*)d_in[4];
  const float* Wv = (const float*)d_in[5];
  const float* bv = (const float*)d_in[6];
  const float* Wo = (const float*)d_in[7];
  const float* bo = (const float*)d_in[8];
  float* out = (float*)d_out;

  char* ws = (char*)d_ws;
  ushort_t* xb  = (ushort_t*)ws;  ws += (size_t)BT * DM * 2;      // x bf16; reused as ctx
  ushort_t* Wqb = (ushort_t*)ws;  ws += (size_t)DM * DM * 2;
  ushort_t* Wkb = (ushort_t*)ws;  ws += (size_t)DM * DM * 2;
  ushort_t* Wvb = (ushort_t*)ws;  ws += (size_t)DM * DM * 2;
  ushort_t* Wob = (ushort_t*)ws;  ws += (size_t)DM * DM * 2;
  ushort_t* Qb  = (ushort_t*)ws;  ws += (size_t)BT * DM * 2;
  ushort_t* Kb  = (ushort_t*)ws;  ws += (size_t)BT * DM * 2;
  ushort_t* Vtb = (ushort_t*)ws;  ws += (size_t)BT * DM * 2;
  ushort_t* ctxb = xb;   // alias: x dead after QKV GEMM

  const int nx4 = BT * DM / 4, nw4 = DM * DM / 4;
  cvt_kernel<<<nx4 / 256, 256, 0, stream>>>(x,  xb,  nx4);
  cvt_kernel<<<nw4 / 256, 256, 0, stream>>>(Wq, Wqb, nw4);
  cvt_kernel<<<nw4 / 256, 256, 0, stream>>>(Wk, Wkb, nw4);
  cvt_kernel<<<nw4 / 256, 256, 0, stream>>>(Wv, Wvb, nw4);
  cvt_kernel<<<nw4 / 256, 256, 0, stream>>>(Wo, Wob, nw4);

  gemm_kernel<0><<<dim3(DM / 128, BT / 128, 3), 256, 0, stream>>>(
      xb, Wqb, Wkb, Wvb, bq, bk, bv, Qb, Kb, Vtb, nullptr);

  attn_kernel<<<dim3(TSEQ / 64, 32), 256, 0, stream>>>(Qb, Kb, Vtb, ctxb);

  gemm_kernel<1><<<dim3(DM / 128, BT / 128, 1), 256, 0, stream>>>(
      ctxb, Wob, nullptr, nullptr, bo, nullptr, nullptr,
      nullptr, nullptr, nullptr, out);
}

// Round 4
// 356.707 us; speedup vs baseline: 1.0994x; 1.0370x over previous
//
#include <hip/hip_runtime.h>
#include <hip/hip_bf16.h>
#include <math.h>

typedef unsigned short ushort_t;
typedef short bf16x8 __attribute__((ext_vector_type(8)));
typedef float f32x4 __attribute__((ext_vector_type(4)));
typedef float f32x16 __attribute__((ext_vector_type(16)));

#define NH 16
#define DH 128
#define DM 2048
#define TSEQ 2048
#define BT 4096   // B*T

__device__ __forceinline__ void async16(const void* g, void* l) {
  __builtin_amdgcn_global_load_lds(
      (const __attribute__((address_space(1))) void*)g,
      (__attribute__((address_space(3))) void*)l, 16, 0, 0);
}

__device__ __forceinline__ f32x4 mfma16(bf16x8 a, bf16x8 b, f32x4 c) {
  return __builtin_amdgcn_mfma_f32_16x16x32_bf16(a, b, c, 0, 0, 0);
}
__device__ __forceinline__ f32x16 mfma32(bf16x8 a, bf16x8 b, f32x16 c) {
  return __builtin_amdgcn_mfma_f32_32x32x16_bf16(a, b, c, 0, 0, 0);
}

__device__ __forceinline__ ushort_t f2bf(float f) {
  __hip_bfloat16 h = __float2bfloat16(f);
  return *reinterpret_cast<ushort_t*>(&h);
}
__device__ __forceinline__ unsigned cvtpk_bf16(float lo, float hi_) {
  unsigned r;
  asm("v_cvt_pk_bf16_f32 %0, %1, %2" : "=v"(r) : "v"(lo), "v"(hi_));
  return r;
}
__device__ __forceinline__ float fexp2(float x) {
  float r; asm("v_exp_f32 %0, %1" : "=v"(r) : "v"(x)); return r;
}

// ---------------- fp32 -> bf16 conversion ----------------
__global__ void cvt_kernel(const float* __restrict__ in, ushort_t* __restrict__ out, int n4) {
  const int i = blockIdx.x * blockDim.x + threadIdx.x;
  if (i >= n4) return;
  const float4 v = reinterpret_cast<const float4*>(in)[i];
  ushort4 u;
  u.x = f2bf(v.x); u.y = f2bf(v.y); u.z = f2bf(v.z); u.w = f2bf(v.w);
  reinterpret_cast<ushort4*>(out)[i] = u;
}

// ---------------- GEMM: C = A[M,K] * W[N,K]^T + bias ----------------
template<int MODE>
__global__ __launch_bounds__(256)
void gemm_kernel(const ushort_t* __restrict__ A,
                 const ushort_t* __restrict__ W_0, const ushort_t* __restrict__ W_1,
                 const ushort_t* __restrict__ W_2,
                 const float* __restrict__ b_0, const float* __restrict__ b_1,
                 const float* __restrict__ b_2,
                 ushort_t* __restrict__ outQ, ushort_t* __restrict__ outK,
                 ushort_t* __restrict__ outVt, float* __restrict__ outF)
{
  constexpr int K = DM;
  __shared__ __attribute__((aligned(16))) ushort_t As[128 * 64];
  __shared__ __attribute__((aligned(16))) ushort_t Bs[128 * 64];

  const int z = (MODE == 0) ? blockIdx.z : 0;
  const ushort_t* Wp = (MODE == 0) ? (z == 0 ? W_0 : (z == 1 ? W_1 : W_2)) : W_0;
  const float* bias  = (MODE == 0) ? (z == 0 ? b_0 : (z == 1 ? b_1 : b_2)) : b_0;

  const int n0 = blockIdx.x * 128;
  const int m0 = blockIdx.y * 128;
  const int tid = threadIdx.x;
  const int w = tid >> 6, l = tid & 63;
  const int wm = w >> 1, wn = w & 1;
  const int l15 = l & 15, l4 = l >> 4;

  f32x4 zero = {0.f, 0.f, 0.f, 0.f};
  f32x4 acc[4][4];
#pragma unroll
  for (int i = 0; i < 4; ++i)
#pragma unroll
    for (int j = 0; j < 4; ++j) acc[i][j] = zero;

  for (int k0 = 0; k0 < K; k0 += 64) {
    __syncthreads();
#pragma unroll
    for (int i = 0; i < 4; ++i) {
      const int rb = (i * 4 + w) * 8;
      const int r = rb + (l >> 3);
      const int c = ((l & 7) * 8) ^ ((r & 7) * 8);   // pre-swizzled source col
      async16(A  + (size_t)(m0 + r) * K + k0 + c, &As[rb * 64]);
      async16(Wp + (size_t)(n0 + r) * K + k0 + c, &Bs[rb * 64]);
    }
    __syncthreads();
#pragma unroll
    for (int ks = 0; ks < 2; ++ks) {
      bf16x8 af[4], bfr[4];
#pragma unroll
      for (int mf = 0; mf < 4; ++mf) {
        const int row = wm * 64 + mf * 16 + l15;
        const int byte_ = row * 128 + ((l4 * 16 + ks * 64) ^ ((row & 7) << 4));
        af[mf] = *reinterpret_cast<const bf16x8*>(reinterpret_cast<const char*>(As) + byte_);
      }
#pragma unroll
      for (int nf = 0; nf < 4; ++nf) {
        const int row = wn * 64 + nf * 16 + l15;
        const int byte_ = row * 128 + ((l4 * 16 + ks * 64) ^ ((row & 7) << 4));
        bfr[nf] = *reinterpret_cast<const bf16x8*>(reinterpret_cast<const char*>(Bs) + byte_);
      }
#pragma unroll
      for (int mf = 0; mf < 4; ++mf)
#pragma unroll
        for (int nf = 0; nf < 4; ++nf)
          acc[mf][nf] = mfma16(af[mf], bfr[nf], acc[mf][nf]);
    }
  }

#pragma unroll
  for (int nf = 0; nf < 4; ++nf) {
    const int n = n0 + wn * 64 + nf * 16 + l15;
    const float bv = bias[n];
#pragma unroll
    for (int mf = 0; mf < 4; ++mf) {
#pragma unroll
      for (int r = 0; r < 4; ++r) {
        const int m = m0 + wm * 64 + mf * 16 + l4 * 4 + r;
        const float v = acc[mf][nf][r] + bv;
        if (MODE == 1) {
          outF[(size_t)m * DM + n] = v;
        } else {
          const int b = m >> 11, t = m & 2047;
          const int hh = n >> 7, d = n & 127;
          const ushort_t val = f2bf(v);
          if (z == 2) {
            outVt[((size_t)(b * NH + hh) * DH + d) * TSEQ + t] = val;   // V transposed
          } else {
            ushort_t* dst = (z == 0) ? outQ : outK;
            dst[((size_t)(b * NH + hh) * TSEQ + t) * DH + d] = val;
          }
        }
      }
    }
  }
}

// ---------------- causal flash attention (8-wave-ladder structure) ----------------
// grid: (16 q-tiles of 128, 32 b*h). block 256 = 4 waves, each wave 32 q rows.
// Swapped QK^T: S^T = mfma32(K_frag, Q_frag) -> lane holds 32 P values of ONE q row.
// PV as O^T = mfma32(V^T_frag, P^T_frag) -> alpha/l stay lane-local.
__device__ __forceinline__ void stage_kv(const ushort_t* __restrict__ Kg,
                                         const ushort_t* __restrict__ Vt,
                                         size_t kbase, size_t vbase, int kv0,
                                         ushort_t* KsB, ushort_t* VsB, int tid)
{
#pragma unroll
  for (int i = 0; i < 4; ++i) {           // K tile [64 kv][128 d], 16KB
    const int idx = i * 256 + tid;
    const int r = idx >> 4, ch = idx & 15;
    const int c = (ch ^ (r & 7)) * 8;     // pre-swizzled source chunk
    async16(Kg + kbase + (size_t)(kv0 + r) * DH + c, KsB + idx * 8);
  }
#pragma unroll
  for (int i = 0; i < 4; ++i) {           // V^T tile [128 d][64 kv], 16KB
    const int idx = i * 256 + tid;
    const int d = idx >> 3, ch = idx & 7;
    const int c = (ch ^ (d & 7)) * 8;
    async16(Vt + vbase + (size_t)d * TSEQ + kv0 + c, VsB + idx * 8);
  }
}

__global__ __launch_bounds__(256)
void attn_kernel(const ushort_t* __restrict__ Q, const ushort_t* __restrict__ Kg,
                 const ushort_t* __restrict__ Vt, ushort_t* __restrict__ ctx)
{
  __shared__ __attribute__((aligned(16))) ushort_t Ks[2][64 * 128];
  __shared__ __attribute__((aligned(16))) ushort_t Vs[2][128 * 64];

  const int qt = (int)gridDim.x - 1 - (int)blockIdx.x;   // heavy tiles first
  const int bh = blockIdx.y;
  const int tid = threadIdx.x, w = tid >> 6, l = tid & 63;
  const int l31 = l & 31, hi = l >> 5;
  const size_t kbase = (size_t)bh * TSEQ * DH;
  const size_t vbase = (size_t)bh * DH * TSEQ;
  const int bq0 = qt * 128;
  const int wq0 = bq0 + w * 32;
  const int NT = qt * 2 + 2;              // kv tiles this block needs
  const int q = wq0 + l31;                // this lane's q row
  const float C2 = 0.12753842f;           // log2(e)/sqrt(128)
  const float NEG = -3.0e38f;

  // Q fragments in registers: aq[st] = Q[q][st*16 + hi*8 .. +7]
  bf16x8 aq[8];
  {
    const ushort_t* qp = Q + kbase + (size_t)q * DH + hi * 8;
#pragma unroll
    for (int st = 0; st < 8; ++st)
      aq[st] = *reinterpret_cast<const bf16x8*>(qp + st * 16);
  }

  f32x16 o[4] = {};            // O^T acc: lane q=l31(col), d = d0*32 + crow(r,hi)
  float m_r = NEG, l_r = 0.f;

  stage_kv(Kg, Vt, kbase, vbase, 0, Ks[0], Vs[0], tid);

  for (int kt = 0; kt < NT; ++kt) {
    const int kv0 = kt * 64, cur = kt & 1;
    if (kt + 1 < NT) {
      stage_kv(Kg, Vt, kbase, vbase, kv0 + 64, Ks[cur ^ 1], Vs[cur ^ 1], tid);
      asm volatile("s_waitcnt vmcnt(8)" ::: "memory");
    } else {
      asm volatile("s_waitcnt vmcnt(0)" ::: "memory");
    }
    __syncthreads();

    if (kv0 <= wq0 + 31) {     // wave-uniform: this wave still has unmasked kv here
      // ---- S^T = K x Q^T : 16 MFMA ----
      const char* ksb = reinterpret_cast<const char*>(Ks[cur]);
      f32x16 s0 = {}, s1 = {};
      __builtin_amdgcn_s_setprio(1);
#pragma unroll
      for (int st = 0; st < 8; ++st) {
        const int byt = l31 * 256 + ((hi * 16 + st * 32) ^ ((l31 & 7) << 4));
        bf16x8 ak0 = *reinterpret_cast<const bf16x8*>(ksb + byt);
        bf16x8 ak1 = *reinterpret_cast<const bf16x8*>(ksb + byt + 8192);
        s0 = mfma32(ak0, aq[st], s0);
        s1 = mfma32(ak1, aq[st], s1);
      }
      __builtin_amdgcn_s_setprio(0);

      // ---- causal mask (boundary tiles only) ----
      if (kv0 + 63 > wq0) {
#pragma unroll
        for (int r = 0; r < 16; ++r) {
          const int kvl = kv0 + (r & 3) + 8 * (r >> 2) + 4 * hi;
          if (kvl > q)      s0[r] = NEG;
          if (kvl + 32 > q) s1[r] = NEG;
        }
      }

      // ---- row max: in-lane tree + one cross-half exchange ----
      float t8[8];
#pragma unroll
      for (int r = 0; r < 8; ++r)
        t8[r] = fmaxf(fmaxf(s0[r], s0[r + 8]), fmaxf(s1[r], s1[r + 8]));
#pragma unroll
      for (int r = 0; r < 4; ++r) t8[r] = fmaxf(t8[r], t8[r + 4]);
      float mt = fmaxf(fmaxf(t8[0], t8[1]), fmaxf(t8[2], t8[3]));
      mt = fmaxf(mt, __shfl_xor(mt, 32));

      // ---- online update with defer-max (T13) ----
      const float mnew = fmaxf(m_r, mt);
      if (!__all(mt <= m_r + 16.0f)) {
        const float alpha = fexp2((m_r - mnew) * C2);
        l_r *= alpha;
#pragma unroll
        for (int d0 = 0; d0 < 4; ++d0) o[d0] *= alpha;
        m_r = mnew;
      }

      // ---- P = exp2((S - m)*C2), row sum ----
#pragma unroll
      for (int r = 0; r < 16; ++r) {
        s0[r] = fexp2((s0[r] - m_r) * C2);
        s1[r] = fexp2((s1[r] - m_r) * C2);
      }
      float sm[8];
#pragma unroll
      for (int r = 0; r < 8; ++r) sm[r] = (s0[r] + s0[r + 8]) + (s1[r] + s1[r + 8]);
#pragma unroll
      for (int r = 0; r < 4; ++r) sm[r] += sm[r + 4];
      float ls = (sm[0] + sm[1]) + (sm[2] + sm[3]);
      ls += __shfl_xor(ls, 32);
      l_r += ls;

      // ---- P->bf16 PA fragments (cvt_pk + permlane32_swap) + PV : 16 MFMA ----
      // permlane32_swap(vdst,vsrc): new_vdst[32+i]=old_vsrc[i]; new_vsrc[i]=old_vdst[32+i].
      // vdst MUST be the early word so each half keeps its low-kv words and
      // receives the partner half's words into the upper slots.
      const char* vsb = reinterpret_cast<const char*>(Vs[cur]);
#pragma unroll
      for (int ks = 0; ks < 4; ++ks) {
        float pj[8];
#pragma unroll
        for (int j = 0; j < 8; ++j)
          pj[j] = (ks >> 1) ? s1[(ks & 1) * 8 + j] : s0[(ks & 1) * 8 + j];
        unsigned cA = cvtpk_bf16(pj[0], pj[1]);
        unsigned cB = cvtpk_bf16(pj[2], pj[3]);
        unsigned cC = cvtpk_bf16(pj[4], pj[5]);
        unsigned cD = cvtpk_bf16(pj[6], pj[7]);
        asm volatile("v_permlane32_swap_b32 %0, %1" : "+v"(cA), "+v"(cC));
        asm volatile("v_permlane32_swap_b32 %0, %1" : "+v"(cB), "+v"(cD));
        union { unsigned u[4]; bf16x8 v; } pa;
        pa.u[0] = cA; pa.u[1] = cB; pa.u[2] = cC; pa.u[3] = cD;
        __builtin_amdgcn_s_setprio(1);
#pragma unroll
        for (int d0 = 0; d0 < 4; ++d0) {
          const int byt = (d0 * 32 + l31) * 128 + ((ks * 32 + hi * 16) ^ ((l31 & 7) << 4));
          bf16x8 av = *reinterpret_cast<const bf16x8*>(vsb + byt);
          o[d0] = mfma32(av, pa.v, o[d0]);
        }
        __builtin_amdgcn_s_setprio(0);
      }
    }
    __syncthreads();   // all waves done with buf[cur] before next stage overwrites
  }

  // ---- epilogue: normalize, write merged ctx [B,T,D] bf16 ----
  const size_t obase = (size_t)(bh >> 4) * TSEQ * DM + (size_t)(bh & 15) * DH;
  const float inv = 1.0f / l_r;
  ushort_t* cp = ctx + obase + (size_t)q * DM + hi * 4;
#pragma unroll
  for (int d0 = 0; d0 < 4; ++d0) {
#pragma unroll
    for (int g = 0; g < 4; ++g) {
      ushort4 u;
      u.x = f2bf(o[d0][4 * g + 0] * inv);
      u.y = f2bf(o[d0][4 * g + 1] * inv);
      u.z = f2bf(o[d0][4 * g + 2] * inv);
      u.w = f2bf(o[d0][4 * g + 3] * inv);
      *reinterpret_cast<ushort4*>(cp + d0 * 32 + 8 * g) = u;
    }
  }
}

extern "C" void kernel_launch(void* const* d_in, const int* in_sizes, int n_in,
                              void* d_out, int out_size, void* d_ws, size_t ws_size,
                              hipStream_t stream) {
  const float* x  = (const float*)d_in[0];
  const float* Wq = (const float*)d_in[1];
  const float* bq = (const float*)d_in[2];
  const float* Wk = (const float*)d_in[3];
  const float* bk = (const float*)d_in[4];
  const float* Wv = (const float*)d_in[5];
  const float* bv = (const float*)d_in[6];
  const float* Wo = (const float*)d_in[7];
  const float* bo = (const float*)d_in[8];
  float* out = (float*)d_out;

  char* ws = (char*)d_ws;
  ushort_t* xb  = (ushort_t*)ws;  ws += (size_t)BT * DM * 2;      // x bf16; reused as ctx
  ushort_t* Wqb = (ushort_t*)ws;  ws += (size_t)DM * DM * 2;
  ushort_t* Wkb = (ushort_t*)ws;  ws += (size_t)DM * DM * 2;
  ushort_t* Wvb = (ushort_t*)ws;  ws += (size_t)DM * DM * 2;
  ushort_t* Wob = (ushort_t*)ws;  ws += (size_t)DM * DM * 2;
  ushort_t* Qb  = (ushort_t*)ws;  ws += (size_t)BT * DM * 2;
  ushort_t* Kb  = (ushort_t*)ws;  ws += (size_t)BT * DM * 2;
  ushort_t* Vtb = (ushort_t*)ws;  ws += (size_t)BT * DM * 2;
  ushort_t* ctxb = xb;   // alias: x dead after QKV GEMM

  const int nx4 = BT * DM / 4, nw4 = DM * DM / 4;
  cvt_kernel<<<nx4 / 256, 256, 0, stream>>>(x,  xb,  nx4);
  cvt_kernel<<<nw4 / 256, 256, 0, stream>>>(Wq, Wqb, nw4);
  cvt_kernel<<<nw4 / 256, 256, 0, stream>>>(Wk, Wkb, nw4);
  cvt_kernel<<<nw4 / 256, 256, 0, stream>>>(Wv, Wvb, nw4);
  cvt_kernel<<<nw4 / 256, 256, 0, stream>>>(Wo, Wob, nw4);

  gemm_kernel<0><<<dim3(DM / 128, BT / 128, 3), 256, 0, stream>>>(
      xb, Wqb, Wkb, Wvb, bq, bk, bv, Qb, Kb, Vtb, nullptr);

  attn_kernel<<<dim3(TSEQ / 128, 32), 256, 0, stream>>>(Qb, Kb, Vtb, ctxb);

  gemm_kernel<1><<<dim3(DM / 128, BT / 128, 1), 256, 0, stream>>>(
      ctxb, Wob, nullptr, nullptr, bo, nullptr, nullptr,
      nullptr, nullptr, nullptr, out);
}

// Round 5
// 298.876 us; speedup vs baseline: 1.3121x; 1.1935x over previous
//
#include <hip/hip_runtime.h>
#include <hip/hip_bf16.h>
#include <math.h>

typedef unsigned short ushort_t;
typedef short bf16x8 __attribute__((ext_vector_type(8)));
typedef float f32x4 __attribute__((ext_vector_type(4)));
typedef float f32x16 __attribute__((ext_vector_type(16)));

#define NH 16
#define DH 128
#define DM 2048
#define TSEQ 2048
#define BT 4096   // B*T

__device__ __forceinline__ void async16(const void* g, void* l) {
  __builtin_amdgcn_global_load_lds(
      (const __attribute__((address_space(1))) void*)g,
      (__attribute__((address_space(3))) void*)l, 16, 0, 0);
}

__device__ __forceinline__ f32x4 mfma16(bf16x8 a, bf16x8 b, f32x4 c) {
  return __builtin_amdgcn_mfma_f32_16x16x32_bf16(a, b, c, 0, 0, 0);
}
__device__ __forceinline__ f32x16 mfma32(bf16x8 a, bf16x8 b, f32x16 c) {
  return __builtin_amdgcn_mfma_f32_32x32x16_bf16(a, b, c, 0, 0, 0);
}

__device__ __forceinline__ ushort_t f2bf(float f) {
  __hip_bfloat16 h = __float2bfloat16(f);
  return *reinterpret_cast<ushort_t*>(&h);
}
__device__ __forceinline__ unsigned cvtpk_bf16(float lo, float hi_) {
  unsigned r;
  asm("v_cvt_pk_bf16_f32 %0, %1, %2" : "=v"(r) : "v"(lo), "v"(hi_));
  return r;
}
__device__ __forceinline__ float fexp2(float x) {
  float r; asm("v_exp_f32 %0, %1" : "=v"(r) : "v"(x)); return r;
}

// ---------------- fp32 -> bf16 conversion ----------------
__global__ void cvt_kernel(const float* __restrict__ in, ushort_t* __restrict__ out, int n4) {
  const int i = blockIdx.x * blockDim.x + threadIdx.x;
  if (i >= n4) return;
  const float4 v = reinterpret_cast<const float4*>(in)[i];
  ushort4 u;
  u.x = f2bf(v.x); u.y = f2bf(v.y); u.z = f2bf(v.z); u.w = f2bf(v.w);
  reinterpret_cast<ushort4*>(out)[i] = u;
}

// ---------------- GEMM: C = A[M,K] * W[N,K]^T + bias ----------------
template<int MODE>
__global__ __launch_bounds__(256)
void gemm_kernel(const ushort_t* __restrict__ A,
                 const ushort_t* __restrict__ W_0, const ushort_t* __restrict__ W_1,
                 const ushort_t* __restrict__ W_2,
                 const float* __restrict__ b_0, const float* __restrict__ b_1,
                 const float* __restrict__ b_2,
                 ushort_t* __restrict__ outQ, ushort_t* __restrict__ outK,
                 ushort_t* __restrict__ outVt, float* __restrict__ outF)
{
  constexpr int K = DM;
  __shared__ __attribute__((aligned(16))) ushort_t As[128 * 64];
  __shared__ __attribute__((aligned(16))) ushort_t Bs[128 * 64];

  const int z = (MODE == 0) ? blockIdx.z : 0;
  const ushort_t* Wp = (MODE == 0) ? (z == 0 ? W_0 : (z == 1 ? W_1 : W_2)) : W_0;
  const float* bias  = (MODE == 0) ? (z == 0 ? b_0 : (z == 1 ? b_1 : b_2)) : b_0;

  const int n0 = blockIdx.x * 128;
  const int m0 = blockIdx.y * 128;
  const int tid = threadIdx.x;
  const int w = tid >> 6, l = tid & 63;
  const int wm = w >> 1, wn = w & 1;
  const int l15 = l & 15, l4 = l >> 4;

  f32x4 zero = {0.f, 0.f, 0.f, 0.f};
  f32x4 acc[4][4];
#pragma unroll
  for (int i = 0; i < 4; ++i)
#pragma unroll
    for (int j = 0; j < 4; ++j) acc[i][j] = zero;

  for (int k0 = 0; k0 < K; k0 += 64) {
    __syncthreads();
#pragma unroll
    for (int i = 0; i < 4; ++i) {
      const int rb = (i * 4 + w) * 8;
      const int r = rb + (l >> 3);
      const int c = ((l & 7) * 8) ^ ((r & 7) * 8);   // pre-swizzled source col
      async16(A  + (size_t)(m0 + r) * K + k0 + c, &As[rb * 64]);
      async16(Wp + (size_t)(n0 + r) * K + k0 + c, &Bs[rb * 64]);
    }
    __syncthreads();
#pragma unroll
    for (int ks = 0; ks < 2; ++ks) {
      bf16x8 af[4], bfr[4];
#pragma unroll
      for (int mf = 0; mf < 4; ++mf) {
        const int row = wm * 64 + mf * 16 + l15;
        const int byte_ = row * 128 + ((l4 * 16 + ks * 64) ^ ((row & 7) << 4));
        af[mf] = *reinterpret_cast<const bf16x8*>(reinterpret_cast<const char*>(As) + byte_);
      }
#pragma unroll
      for (int nf = 0; nf < 4; ++nf) {
        const int row = wn * 64 + nf * 16 + l15;
        const int byte_ = row * 128 + ((l4 * 16 + ks * 64) ^ ((row & 7) << 4));
        bfr[nf] = *reinterpret_cast<const bf16x8*>(reinterpret_cast<const char*>(Bs) + byte_);
      }
#pragma unroll
      for (int mf = 0; mf < 4; ++mf)
#pragma unroll
        for (int nf = 0; nf < 4; ++nf)
          acc[mf][nf] = mfma16(af[mf], bfr[nf], acc[mf][nf]);
    }
  }

#pragma unroll
  for (int nf = 0; nf < 4; ++nf) {
    const int n = n0 + wn * 64 + nf * 16 + l15;
    const float bv = bias[n];
#pragma unroll
    for (int mf = 0; mf < 4; ++mf) {
#pragma unroll
      for (int r = 0; r < 4; ++r) {
        const int m = m0 + wm * 64 + mf * 16 + l4 * 4 + r;
        const float v = acc[mf][nf][r] + bv;
        if (MODE == 1) {
          outF[(size_t)m * DM + n] = v;
        } else {
          const int b = m >> 11, t = m & 2047;
          const int hh = n >> 7, d = n & 127;
          const ushort_t val = f2bf(v);
          if (z == 2) {
            outVt[((size_t)(b * NH + hh) * DH + d) * TSEQ + t] = val;   // V transposed
          } else {
            ushort_t* dst = (z == 0) ? outQ : outK;
            dst[((size_t)(b * NH + hh) * TSEQ + t) * DH + d] = val;
          }
        }
      }
    }
  }
}

// ---------------- causal flash attention ----------------
// grid 512 blocks = (16 q-tiles of 128) x (32 b*h), remapped so each XCD owns
// 4 heads (KV working set = 4MB = one L2), pair-balanced qt assignment.
// Raw s_barrier + counted vmcnt: prefetch of tile t+1 stays in flight across
// the barrier (T3/T4); __syncthreads would drain vmcnt(0) and kill it.
__device__ __forceinline__ void stage_kv(const ushort_t* __restrict__ Kg,
                                         const ushort_t* __restrict__ Vt,
                                         size_t kbase, size_t vbase, int kv0,
                                         ushort_t* KsB, ushort_t* VsB, int tid)
{
#pragma unroll
  for (int i = 0; i < 4; ++i) {           // K tile [64 kv][128 d], 16KB
    const int idx = i * 256 + tid;
    const int r = idx >> 4, ch = idx & 15;
    const int c = (ch ^ (r & 7)) * 8;     // pre-swizzled source chunk
    async16(Kg + kbase + (size_t)(kv0 + r) * DH + c, KsB + idx * 8);
  }
#pragma unroll
  for (int i = 0; i < 4; ++i) {           // V^T tile [128 d][64 kv], 16KB
    const int idx = i * 256 + tid;
    const int d = idx >> 3, ch = idx & 7;
    const int c = (ch ^ (d & 7)) * 8;
    async16(Vt + vbase + (size_t)d * TSEQ + kv0 + c, VsB + idx * 8);
  }
}

__global__ __launch_bounds__(256)
void attn_kernel(const ushort_t* __restrict__ Q, const ushort_t* __restrict__ Kg,
                 const ushort_t* __restrict__ Vt, ushort_t* __restrict__ ctx)
{
  __shared__ __attribute__((aligned(16))) ushort_t Ks[2][64 * 128];
  __shared__ __attribute__((aligned(16))) ushort_t Vs[2][128 * 64];

  // XCD-aware remap: fid is dispatch order (x fastest); consecutive fid
  // round-robin XCDs. 4 heads per XCD; qt arranged so slots s and s+32
  // (same-CU pair: all 512 blocks are co-resident) sum to 15.
  const int fid = (int)blockIdx.x + 16 * (int)blockIdx.y;
  const int xcd = fid & 7;
  const int s   = fid >> 3;                       // 0..63 within XCD
  const int bh  = xcd * 4 + (s & 3);
  const int qt  = (s < 32) ? (15 - (s >> 2)) : ((s - 32) >> 2);

  const int tid = threadIdx.x, w = tid >> 6, l = tid & 63;
  const int l31 = l & 31, hi = l >> 5;
  const size_t kbase = (size_t)bh * TSEQ * DH;
  const size_t vbase = (size_t)bh * DH * TSEQ;
  const int bq0 = qt * 128;
  const int wq0 = bq0 + w * 32;
  const int NT = qt * 2 + 2;              // kv tiles this block needs
  const int q = wq0 + l31;                // this lane's q row
  const float C2 = 0.12753842f;           // log2(e)/sqrt(128)
  const float NEG = -3.0e38f;

  // Q fragments in registers: aq[st] = Q[q][st*16 + hi*8 .. +7]
  bf16x8 aq[8];
  {
    const ushort_t* qp = Q + kbase + (size_t)q * DH + hi * 8;
#pragma unroll
    for (int st = 0; st < 8; ++st)
      aq[st] = *reinterpret_cast<const bf16x8*>(qp + st * 16);
  }

  f32x16 o[4] = {};            // O^T acc: lane q=l31(col), d = d0*32 + crow(r,hi)
  float m_r = NEG, l_r = 0.f;

  stage_kv(Kg, Vt, kbase, vbase, 0, Ks[0], Vs[0], tid);

  for (int kt = 0; kt < NT; ++kt) {
    const int kv0 = kt * 64, cur = kt & 1;
    if (kt + 1 < NT) {
      stage_kv(Kg, Vt, kbase, vbase, kv0 + 64, Ks[cur ^ 1], Vs[cur ^ 1], tid);
      asm volatile("s_waitcnt vmcnt(8)" ::: "memory");   // tile t landed; t+1 in flight
    } else {
      asm volatile("s_waitcnt vmcnt(0)" ::: "memory");
    }
    __builtin_amdgcn_s_barrier();          // (A) buf[cur] ready; prefetch NOT drained

    if (kv0 <= wq0 + 31) {     // wave-uniform: this wave still has unmasked kv here
      // ---- S^T = K x Q^T : 16 MFMA ----
      const char* ksb = reinterpret_cast<const char*>(Ks[cur]);
      f32x16 s0 = {}, s1 = {};
      __builtin_amdgcn_s_setprio(1);
#pragma unroll
      for (int st = 0; st < 8; ++st) {
        const int byt = l31 * 256 + ((hi * 16 + st * 32) ^ ((l31 & 7) << 4));
        bf16x8 ak0 = *reinterpret_cast<const bf16x8*>(ksb + byt);
        bf16x8 ak1 = *reinterpret_cast<const bf16x8*>(ksb + byt + 8192);
        s0 = mfma32(ak0, aq[st], s0);
        s1 = mfma32(ak1, aq[st], s1);
      }
      __builtin_amdgcn_s_setprio(0);

      // ---- causal mask (boundary tiles only) ----
      if (kv0 + 63 > wq0) {
#pragma unroll
        for (int r = 0; r < 16; ++r) {
          const int kvl = kv0 + (r & 3) + 8 * (r >> 2) + 4 * hi;
          if (kvl > q)      s0[r] = NEG;
          if (kvl + 32 > q) s1[r] = NEG;
        }
      }

      // ---- row max: in-lane tree + one cross-half exchange ----
      float t8[8];
#pragma unroll
      for (int r = 0; r < 8; ++r)
        t8[r] = fmaxf(fmaxf(s0[r], s0[r + 8]), fmaxf(s1[r], s1[r + 8]));
#pragma unroll
      for (int r = 0; r < 4; ++r) t8[r] = fmaxf(t8[r], t8[r + 4]);
      float mt = fmaxf(fmaxf(t8[0], t8[1]), fmaxf(t8[2], t8[3]));
      mt = fmaxf(mt, __shfl_xor(mt, 32));

      // ---- online update with defer-max (T13) ----
      const float mnew = fmaxf(m_r, mt);
      if (!__all(mt <= m_r + 16.0f)) {
        const float alpha = fexp2((m_r - mnew) * C2);
        l_r *= alpha;
#pragma unroll
        for (int d0 = 0; d0 < 4; ++d0) o[d0] *= alpha;
        m_r = mnew;
      }

      // ---- P = exp2((S - m)*C2), row sum ----
#pragma unroll
      for (int r = 0; r < 16; ++r) {
        s0[r] = fexp2((s0[r] - m_r) * C2);
        s1[r] = fexp2((s1[r] - m_r) * C2);
      }
      float sm[8];
#pragma unroll
      for (int r = 0; r < 8; ++r) sm[r] = (s0[r] + s0[r + 8]) + (s1[r] + s1[r + 8]);
#pragma unroll
      for (int r = 0; r < 4; ++r) sm[r] += sm[r + 4];
      float ls = (sm[0] + sm[1]) + (sm[2] + sm[3]);
      ls += __shfl_xor(ls, 32);
      l_r += ls;

      // ---- P->bf16 PA fragments (cvt_pk + permlane32_swap) + PV : 16 MFMA ----
      // permlane32_swap(vdst,vsrc): new_vdst[32+i]=old_vsrc[i]; new_vsrc[i]=old_vdst[32+i].
      const char* vsb = reinterpret_cast<const char*>(Vs[cur]);
#pragma unroll
      for (int ks = 0; ks < 4; ++ks) {
        float pj[8];
#pragma unroll
        for (int j = 0; j < 8; ++j)
          pj[j] = (ks >> 1) ? s1[(ks & 1) * 8 + j] : s0[(ks & 1) * 8 + j];
        unsigned cA = cvtpk_bf16(pj[0], pj[1]);
        unsigned cB = cvtpk_bf16(pj[2], pj[3]);
        unsigned cC = cvtpk_bf16(pj[4], pj[5]);
        unsigned cD = cvtpk_bf16(pj[6], pj[7]);
        asm volatile("v_permlane32_swap_b32 %0, %1" : "+v"(cA), "+v"(cC));
        asm volatile("v_permlane32_swap_b32 %0, %1" : "+v"(cB), "+v"(cD));
        union { unsigned u[4]; bf16x8 v; } pa;
        pa.u[0] = cA; pa.u[1] = cB; pa.u[2] = cC; pa.u[3] = cD;
        __builtin_amdgcn_s_setprio(1);
#pragma unroll
        for (int d0 = 0; d0 < 4; ++d0) {
          const int byt = (d0 * 32 + l31) * 128 + ((ks * 32 + hi * 16) ^ ((l31 & 7) << 4));
          bf16x8 av = *reinterpret_cast<const bf16x8*>(vsb + byt);
          o[d0] = mfma32(av, pa.v, o[d0]);
        }
        __builtin_amdgcn_s_setprio(0);
      }
    }
    asm volatile("" ::: "memory");         // keep ds_reads above barrier (B)
    __builtin_amdgcn_s_barrier();          // (B) buf[cur] free for stage(t+2)
  }

  // ---- epilogue: normalize, write merged ctx [B,T,D] bf16 ----
  const size_t obase = (size_t)(bh >> 4) * TSEQ * DM + (size_t)(bh & 15) * DH;
  const float inv = 1.0f / l_r;
  ushort_t* cp = ctx + obase + (size_t)q * DM + hi * 4;
#pragma unroll
  for (int d0 = 0; d0 < 4; ++d0) {
#pragma unroll
    for (int g = 0; g < 4; ++g) {
      ushort4 u;
      u.x = f2bf(o[d0][4 * g + 0] * inv);
      u.y = f2bf(o[d0][4 * g + 1] * inv);
      u.z = f2bf(o[d0][4 * g + 2] * inv);
      u.w = f2bf(o[d0][4 * g + 3] * inv);
      *reinterpret_cast<ushort4*>(cp + d0 * 32 + 8 * g) = u;
    }
  }
}

extern "C" void kernel_launch(void* const* d_in, const int* in_sizes, int n_in,
                              void* d_out, int out_size, void* d_ws, size_t ws_size,
                              hipStream_t stream) {
  const float* x  = (const float*)d_in[0];
  const float* Wq = (const float*)d_in[1];
  const float* bq = (const float*)d_in[2];
  const float* Wk = (const float*)d_in[3];
  const float* bk = (const float*)d_in[4];
  const float* Wv = (const float*)d_in[5];
  const float* bv = (const float*)d_in[6];
  const float* Wo = (const float*)d_in[7];
  const float* bo = (const float*)d_in[8];
  float* out = (float*)d_out;

  char* ws = (char*)d_ws;
  ushort_t* xb  = (ushort_t*)ws;  ws += (size_t)BT * DM * 2;      // x bf16; reused as ctx
  ushort_t* Wqb = (ushort_t*)ws;  ws += (size_t)DM * DM * 2;
  ushort_t* Wkb = (ushort_t*)ws;  ws += (size_t)DM * DM * 2;
  ushort_t* Wvb = (ushort_t*)ws;  ws += (size_t)DM * DM * 2;
  ushort_t* Wob = (ushort_t*)ws;  ws += (size_t)DM * DM * 2;
  ushort_t* Qb  = (ushort_t*)ws;  ws += (size_t)BT * DM * 2;
  ushort_t* Kb  = (ushort_t*)ws;  ws += (size_t)BT * DM * 2;
  ushort_t* Vtb = (ushort_t*)ws;  ws += (size_t)BT * DM * 2;
  ushort_t* ctxb = xb;   // alias: x dead after QKV GEMM

  const int nx4 = BT * DM / 4, nw4 = DM * DM / 4;
  cvt_kernel<<<nx4 / 256, 256, 0, stream>>>(x,  xb,  nx4);
  cvt_kernel<<<nw4 / 256, 256, 0, stream>>>(Wq, Wqb, nw4);
  cvt_kernel<<<nw4 / 256, 256, 0, stream>>>(Wk, Wkb, nw4);
  cvt_kernel<<<nw4 / 256, 256, 0, stream>>>(Wv, Wvb, nw4);
  cvt_kernel<<<nw4 / 256, 256, 0, stream>>>(Wo, Wob, nw4);

  gemm_kernel<0><<<dim3(DM / 128, BT / 128, 3), 256, 0, stream>>>(
      xb, Wqb, Wkb, Wvb, bq, bk, bv, Qb, Kb, Vtb, nullptr);

  attn_kernel<<<dim3(TSEQ / 128, 32), 256, 0, stream>>>(Qb, Kb, Vtb, ctxb);

  gemm_kernel<1><<<dim3(DM / 128, BT / 128, 1), 256, 0, stream>>>(
      ctxb, Wob, nullptr, nullptr, bo, nullptr, nullptr,
      nullptr, nullptr, nullptr, out);
}